// Round 1
// baseline (339.017 us; speedup 1.0000x reference)
//
#include <hip/hip_runtime.h>

typedef unsigned short u16;
typedef __attribute__((ext_vector_type(8))) short bf16x8;
typedef __attribute__((ext_vector_type(4))) float f32x4;
typedef __attribute__((ext_vector_type(4))) unsigned short u16x4;

#define DEVI __device__ __forceinline__

constexpr float L2GAMMA = -0.15200309344504997f; // log2(0.9)
constexpr float INV_SQRT_H = 0.0625f;            // 1/sqrt(256)

DEVI u16 f2bf(float x) {
  union { float f; unsigned u; } v; v.f = x;
  unsigned r = v.u + 0x7FFFu + ((v.u >> 16) & 1u);
  return (u16)(r >> 16);
}

// ---- kernel 0a: x fp32 -> bf16 ------------------------------------------
__global__ void cvt_x_kernel(const float4* __restrict__ src, u16x4* __restrict__ dst, int n4) {
  int stride = gridDim.x * blockDim.x;
  for (int i = blockIdx.x * blockDim.x + threadIdx.x; i < n4; i += stride) {
    float4 v = src[i];
    u16x4 o; o.x = f2bf(v.x); o.y = f2bf(v.y); o.z = f2bf(v.z); o.w = f2bf(v.w);
    dst[i] = o;
  }
}

// ---- kernel 0b: W_Q|W_K|W_V (each 256x1024 fp32) -> Wb[768][1024] bf16 ---
__global__ void cvt_w_kernel(const float4* __restrict__ wq, const float4* __restrict__ wk,
                             const float4* __restrict__ wv, u16x4* __restrict__ dst) {
  int i = blockIdx.x * blockDim.x + threadIdx.x; // 0..196607 (grid exactly covers)
  int w = i >> 16, off = i & 65535;
  const float4* s = (w == 0) ? wq : ((w == 1) ? wk : wv);
  float4 v = s[off];
  u16x4 o; o.x = f2bf(v.x); o.y = f2bf(v.y); o.z = f2bf(v.z); o.w = f2bf(v.w);
  dst[(w << 16) + off] = o;
}

// ---- kernel 1: QKV GEMM  C[16384x768] = Xb[16384x1024] * Wb^T ------------
// 128x128 tile, BK=32, 4 waves (wave tile 64x64 = 4x4 frags of 16x16x32).
// Epilogue: n<256 -> Qb row-major, n<512 -> Kb row-major, else Vt[b][h][l].
__global__ __launch_bounds__(256) void qkv_gemm_kernel(const u16* __restrict__ Xb, const u16* __restrict__ Wb,
                                                       u16* __restrict__ Qb, u16* __restrict__ Kb,
                                                       u16* __restrict__ Vt) {
  __shared__ u16 Alds[128 * 32];
  __shared__ u16 Blds[128 * 32];
  const int nt = blockIdx.x;      // 0..5
  const int m0 = blockIdx.y * 128;
  const int n0 = nt * 128;
  const int tid = threadIdx.x;
  const int wid = tid >> 6, lane = tid & 63;
  const int wm = wid >> 1, wn = wid & 1;
  const int lrow = lane & 15, lk = (lane >> 4) * 8;
  const int sRow = lane >> 2, sCol = (lane & 3) * 8;

  f32x4 acc[4][4] = {};

  for (int kt = 0; kt < 32; ++kt) {
    const int k0 = kt * 32;
#pragma unroll
    for (int r = 0; r < 2; ++r) {
      const int chunk = wid * 2 + r;          // 0..7, wave-uniform
      const int row = chunk * 16 + sRow;
      const u16* gA = Xb + (size_t)(m0 + row) * 1024 + k0 + sCol;
      const u16* gB = Wb + (size_t)(n0 + row) * 1024 + k0 + sCol;
      __builtin_amdgcn_global_load_lds((const __attribute__((address_space(1))) void*)gA,
                                       (__attribute__((address_space(3))) void*)&Alds[chunk * 512], 16, 0, 0);
      __builtin_amdgcn_global_load_lds((const __attribute__((address_space(1))) void*)gB,
                                       (__attribute__((address_space(3))) void*)&Blds[chunk * 512], 16, 0, 0);
    }
    __syncthreads();
    bf16x8 a[4], b[4];
#pragma unroll
    for (int mf = 0; mf < 4; ++mf) a[mf] = *(const bf16x8*)&Alds[(wm * 64 + mf * 16 + lrow) * 32 + lk];
#pragma unroll
    for (int nf = 0; nf < 4; ++nf) b[nf] = *(const bf16x8*)&Blds[(wn * 64 + nf * 16 + lrow) * 32 + lk];
#pragma unroll
    for (int mf = 0; mf < 4; ++mf)
#pragma unroll
      for (int nf = 0; nf < 4; ++nf)
        acc[mf][nf] = __builtin_amdgcn_mfma_f32_16x16x32_bf16(a[mf], b[nf], acc[mf][nf], 0, 0, 0);
    __syncthreads();
  }

  const int rbase = (lane >> 4) * 4;
  if (nt < 4) {
    u16* Dst = (nt < 2) ? Qb : Kb;
    const int cb = (nt < 2) ? n0 : (n0 - 256);
#pragma unroll
    for (int mf = 0; mf < 4; ++mf)
#pragma unroll
      for (int nf = 0; nf < 4; ++nf) {
        const int gm = m0 + wm * 64 + mf * 16 + rbase;
        const int c = cb + wn * 64 + nf * 16 + lrow;
#pragma unroll
        for (int r = 0; r < 4; ++r) Dst[(size_t)(gm + r) * 256 + c] = f2bf(acc[mf][nf][r]);
      }
  } else {
#pragma unroll
    for (int mf = 0; mf < 4; ++mf)
#pragma unroll
      for (int nf = 0; nf < 4; ++nf) {
        const int gm = m0 + wm * 64 + mf * 16 + rbase;
        const int h = n0 - 512 + wn * 64 + nf * 16 + lrow;
        const int bb = gm >> 12, l = gm & 4095;
        u16x4 pk;
        pk.x = f2bf(acc[mf][nf][0]); pk.y = f2bf(acc[mf][nf][1]);
        pk.z = f2bf(acc[mf][nf][2]); pk.w = f2bf(acc[mf][nf][3]);
        *(u16x4*)&Vt[((size_t)bb * 256 + h) * 4096 + l] = pk;
      }
  }
}

// ---- kernel 2: decay attention (flash-style, no softmax) -----------------
// QB=32, KB=64, 8 waves: S wave-grid 2(m)x4(n), PV wave-grid 2(m)x4(h).
// Pairing (p, 127-p) => exactly 65 j-tiles per WG. Grid flat 256, XCD-aware
// decode keeps each batch's K/V on 2 XCDs.
__global__ __launch_bounds__(512) void attn_kernel(const u16* __restrict__ Qb, const u16* __restrict__ Kb,
                                                   const u16* __restrict__ Vt, float* __restrict__ out) {
  __shared__ u16 Plds[32 * 72];
  const int id = blockIdx.x;           // 0..255
  const int r8 = id & 7, q8 = id >> 3;
  const int b = r8 >> 1;
  const int p = (r8 & 1) * 32 + q8;    // 0..63
  const int tid = threadIdx.x;
  const int wid = tid >> 6, lane = tid & 63;
  const int wm = wid >> 2, wn = wid & 3;
  const int lrow = lane & 15, lkg = lane >> 4, lk = lkg * 8;
  const size_t bQK = (size_t)b * 4096 * 256;

  for (int half = 0; half < 2; ++half) {
    const int qt = half ? (127 - p) : p;  // q-tile index (32 rows each)
    const int qbase = qt * 32;
    bf16x8 qf[8];
    const u16* Qrow = Qb + bQK + (size_t)(qbase + wm * 16 + lrow) * 256;
#pragma unroll
    for (int kf = 0; kf < 8; ++kf) qf[kf] = *(const bf16x8*)&Qrow[kf * 32 + lk];
    f32x4 oacc[4] = {};
    const int nj = (qt >> 1) + 1;
    for (int jt = 0; jt < nj; ++jt) {
      const int kbase = jt * 64;
      // S = Q K^T for this wave's 16x16 slice, K-dim = 256
      f32x4 s = {};
      const u16* Krow = Kb + bQK + (size_t)(kbase + wn * 16 + lrow) * 256;
#pragma unroll
      for (int kf = 0; kf < 8; ++kf) {
        bf16x8 kfr = *(const bf16x8*)&Krow[kf * 32 + lk];
        s = __builtin_amdgcn_mfma_f32_16x16x32_bf16(qf[kf], kfr, s, 0, 0, 0);
      }
      // decay mask + scale, write P (bf16) to LDS
      const int qg = qbase + wm * 16 + lkg * 4;
      const int kg = kbase + wn * 16 + lrow;
#pragma unroll
      for (int r = 0; r < 4; ++r) {
        const int d = qg + r - kg;
        const float pv = (d >= 0) ? s[r] * exp2f((float)d * L2GAMMA) * INV_SQRT_H : 0.0f;
        Plds[(wm * 16 + lkg * 4 + r) * 72 + wn * 16 + lrow] = f2bf(pv);
      }
      __syncthreads();
      // O += P V  (K-dim = 64)
#pragma unroll
      for (int ks = 0; ks < 2; ++ks) {
        const bf16x8 pa = *(const bf16x8*)&Plds[(wm * 16 + lrow) * 72 + ks * 32 + lk];
#pragma unroll
        for (int nf = 0; nf < 4; ++nf) {
          const bf16x8 vb = *(const bf16x8*)&Vt[((size_t)b * 256 + wn * 64 + nf * 16 + lrow) * 4096 + kbase + ks * 32 + lk];
          oacc[nf] = __builtin_amdgcn_mfma_f32_16x16x32_bf16(pa, vb, oacc[nf], 0, 0, 0);
        }
      }
      __syncthreads();
    }
    float* obase = out + ((size_t)b * 4096 + qbase + wm * 16 + lkg * 4) * 256 + wn * 64 + lrow;
#pragma unroll
    for (int nf = 0; nf < 4; ++nf)
#pragma unroll
      for (int r = 0; r < 4; ++r)
        obase[(size_t)r * 256 + nf * 16] = oacc[nf][r];
  }
}

extern "C" void kernel_launch(void* const* d_in, const int* in_sizes, int n_in,
                              void* d_out, int out_size, void* d_ws, size_t ws_size,
                              hipStream_t stream) {
  const float* x  = (const float*)d_in[0];
  const float* wq = (const float*)d_in[1];
  const float* wk = (const float*)d_in[2];
  const float* wv = (const float*)d_in[3];
  float* out = (float*)d_out;
  char* ws = (char*)d_ws;
  // workspace layout (bytes)
  u16* Xb = (u16*)(ws);                          // 16384*1024*2 = 33,554,432
  u16* Wb = (u16*)(ws + (size_t)33554432);       //   768*1024*2 =  1,572,864
  u16* Qb = (u16*)(ws + (size_t)35127296);       // 16384*256*2  =  8,388,608
  u16* Kb = (u16*)(ws + (size_t)43515904);       //  8,388,608
  u16* Vt = (u16*)(ws + (size_t)51904512);       //  8,388,608  (end 60,293,120)

  hipLaunchKernelGGL(cvt_x_kernel, dim3(2048), dim3(256), 0, stream,
                     (const float4*)x, (u16x4*)Xb, 4194304);
  hipLaunchKernelGGL(cvt_w_kernel, dim3(768), dim3(256), 0, stream,
                     (const float4*)wq, (const float4*)wk, (const float4*)wv, (u16x4*)Wb);
  hipLaunchKernelGGL(qkv_gemm_kernel, dim3(6, 128), dim3(256), 0, stream, Xb, Wb, Qb, Kb, Vt);
  hipLaunchKernelGGL(attn_kernel, dim3(256), dim3(512), 0, stream, Qb, Kb, Vt, out);
}

// Round 2
// 105.488 us; speedup vs baseline: 3.2138x; 3.2138x over previous
//
#include <hip/hip_runtime.h>

typedef unsigned short u16;
typedef __attribute__((ext_vector_type(8))) short bf16x8;
typedef __attribute__((ext_vector_type(4))) float f32x4;
typedef __attribute__((ext_vector_type(4))) unsigned short u16x4;

#define DEVI __device__ __forceinline__

constexpr float L2GAMMA = -0.15200309344504997f; // log2(0.9)
constexpr float INV_SQRT_H = 0.0625f;            // 1/sqrt(256)

DEVI u16 f2bf(float x) {
  union { float f; unsigned u; } v; v.f = x;
  unsigned r = v.u + 0x7FFFu + ((v.u >> 16) & 1u);
  return (u16)(r >> 16);
}

// ---- kernel 0a: x fp32 -> bf16 ------------------------------------------
__global__ void cvt_x_kernel(const float4* __restrict__ src, u16x4* __restrict__ dst, int n4) {
  int stride = gridDim.x * blockDim.x;
  for (int i = blockIdx.x * blockDim.x + threadIdx.x; i < n4; i += stride) {
    float4 v = src[i];
    u16x4 o; o.x = f2bf(v.x); o.y = f2bf(v.y); o.z = f2bf(v.z); o.w = f2bf(v.w);
    dst[i] = o;
  }
}

// ---- kernel 0b: W_Q|W_K|W_V (each 256x1024 fp32) -> Wb[768][1024] bf16 ---
__global__ void cvt_w_kernel(const float4* __restrict__ wq, const float4* __restrict__ wk,
                             const float4* __restrict__ wv, u16x4* __restrict__ dst) {
  int i = blockIdx.x * blockDim.x + threadIdx.x; // 0..196607 (grid exactly covers)
  int w = i >> 16, off = i & 65535;
  const float4* s = (w == 0) ? wq : ((w == 1) ? wk : wv);
  float4 v = s[off];
  u16x4 o; o.x = f2bf(v.x); o.y = f2bf(v.y); o.z = f2bf(v.z); o.w = f2bf(v.w);
  dst[(w << 16) + off] = o;
}

// ---- kernel 1: QKV GEMM  C[16384x768] = Xb[16384x1024] * Wb^T ------------
__global__ __launch_bounds__(256) void qkv_gemm_kernel(const u16* __restrict__ Xb, const u16* __restrict__ Wb,
                                                       u16* __restrict__ Qb, u16* __restrict__ Kb,
                                                       u16* __restrict__ Vt) {
  __shared__ u16 Alds[128 * 32];
  __shared__ u16 Blds[128 * 32];
  const int nt = blockIdx.x;      // 0..5
  const int m0 = blockIdx.y * 128;
  const int n0 = nt * 128;
  const int tid = threadIdx.x;
  const int wid = tid >> 6, lane = tid & 63;
  const int wm = wid >> 1, wn = wid & 1;
  const int lrow = lane & 15, lk = (lane >> 4) * 8;
  const int sRow = lane >> 2, sCol = (lane & 3) * 8;

  f32x4 acc[4][4] = {};

  for (int kt = 0; kt < 32; ++kt) {
    const int k0 = kt * 32;
#pragma unroll
    for (int r = 0; r < 2; ++r) {
      const int chunk = wid * 2 + r;          // 0..7, wave-uniform
      const int row = chunk * 16 + sRow;
      const u16* gA = Xb + (size_t)(m0 + row) * 1024 + k0 + sCol;
      const u16* gB = Wb + (size_t)(n0 + row) * 1024 + k0 + sCol;
      __builtin_amdgcn_global_load_lds((const __attribute__((address_space(1))) void*)gA,
                                       (__attribute__((address_space(3))) void*)&Alds[chunk * 512], 16, 0, 0);
      __builtin_amdgcn_global_load_lds((const __attribute__((address_space(1))) void*)gB,
                                       (__attribute__((address_space(3))) void*)&Blds[chunk * 512], 16, 0, 0);
    }
    __syncthreads();
    bf16x8 a[4], b[4];
#pragma unroll
    for (int mf = 0; mf < 4; ++mf) a[mf] = *(const bf16x8*)&Alds[(wm * 64 + mf * 16 + lrow) * 32 + lk];
#pragma unroll
    for (int nf = 0; nf < 4; ++nf) b[nf] = *(const bf16x8*)&Blds[(wn * 64 + nf * 16 + lrow) * 32 + lk];
#pragma unroll
    for (int mf = 0; mf < 4; ++mf)
#pragma unroll
      for (int nf = 0; nf < 4; ++nf)
        acc[mf][nf] = __builtin_amdgcn_mfma_f32_16x16x32_bf16(a[mf], b[nf], acc[mf][nf], 0, 0, 0);
    __syncthreads();
  }

  const int rbase = (lane >> 4) * 4;
  if (nt < 4) {
    u16* Dst = (nt < 2) ? Qb : Kb;
    const int cb = (nt < 2) ? n0 : (n0 - 256);
#pragma unroll
    for (int mf = 0; mf < 4; ++mf)
#pragma unroll
      for (int nf = 0; nf < 4; ++nf) {
        const int gm = m0 + wm * 64 + mf * 16 + rbase;
        const int c = cb + wn * 64 + nf * 16 + lrow;
#pragma unroll
        for (int r = 0; r < 4; ++r) Dst[(size_t)(gm + r) * 256 + c] = f2bf(acc[mf][nf][r]);
      }
  } else {
#pragma unroll
    for (int mf = 0; mf < 4; ++mf)
#pragma unroll
      for (int nf = 0; nf < 4; ++nf) {
        const int gm = m0 + wm * 64 + mf * 16 + rbase;
        const int h = n0 - 512 + wn * 64 + nf * 16 + lrow;
        const int bb = gm >> 12, l = gm & 4095;
        u16x4 pk;
        pk.x = f2bf(acc[mf][nf][0]); pk.y = f2bf(acc[mf][nf][1]);
        pk.z = f2bf(acc[mf][nf][2]); pk.w = f2bf(acc[mf][nf][3]);
        *(u16x4*)&Vt[((size_t)bb * 256 + h) * 4096 + l] = pk;
      }
  }
}

// ---- kernel 2: WINDOWED decay attention ----------------------------------
// gamma^320 ~ 2.5e-15 => keys older than the aligned 256..319 window are
// numerically zero in fp32. QB=32 rows/WG, KB=64, 4 waves (256 thr).
// Wave wid owns S k-columns [wid*16,+16) and O h-columns [wid*64,+64).
// Grid 512 = B*128 q-tiles, XCD-chunked remap for K/V L2 residency.
__global__ __launch_bounds__(256) void attn_kernel(const u16* __restrict__ Qb, const u16* __restrict__ Kb,
                                                   const u16* __restrict__ Vt, float* __restrict__ out) {
  __shared__ u16 Plds[32 * 72];
  const int raw = blockIdx.x;                 // 0..511
  const int aid = (raw & 7) * 64 + (raw >> 3);  // XCD-chunked: 64 consecutive ids per XCD
  const int b = aid >> 7;                     // 0..3
  const int qt = aid & 127;                   // 0..127
  const int qb = qt * 32;
  const int tid = threadIdx.x;
  const int wid = tid >> 6, lane = tid & 63;
  const int lrow = lane & 15, lkg = lane >> 4, lk = lkg * 8;
  const size_t bQK = (size_t)b * 4096 * 256;

  // Q fragments in registers: rows qb + mf*16 + lrow, full H=256
  bf16x8 qf[2][8];
#pragma unroll
  for (int mf = 0; mf < 2; ++mf) {
    const u16* Qrow = Qb + bQK + (size_t)(qb + mf * 16 + lrow) * 256;
#pragma unroll
    for (int kf = 0; kf < 8; ++kf) qf[mf][kf] = *(const bf16x8*)&Qrow[kf * 32 + lk];
  }

  int kstart = qb - 256; if (kstart < 0) kstart = 0; kstart &= ~63;
  const int njt = (qb + 32 - kstart + 63) >> 6;   // <= 5; kend = 64*ceil((qb+32)/64) <= 4096

  f32x4 oacc[2][4] = {};

  for (int jt = 0; jt < njt; ++jt) {
    const int kb = kstart + jt * 64;
    // ---- S = Q K^T for this wave's 32x16 slice (k-cols wid*16..+15) ----
    f32x4 s[2] = {};
    const u16* Krow = Kb + bQK + (size_t)(kb + wid * 16 + lrow) * 256;
#pragma unroll
    for (int kf = 0; kf < 8; ++kf) {
      const bf16x8 kfr = *(const bf16x8*)&Krow[kf * 32 + lk];
      s[0] = __builtin_amdgcn_mfma_f32_16x16x32_bf16(qf[0][kf], kfr, s[0], 0, 0, 0);
      s[1] = __builtin_amdgcn_mfma_f32_16x16x32_bf16(qf[1][kf], kfr, s[1], 0, 0, 0);
    }
    // ---- decay mask + scale -> P (bf16) in LDS ----
    const int kg = kb + wid * 16 + lrow;
#pragma unroll
    for (int mf = 0; mf < 2; ++mf) {
      const int qg = qb + mf * 16 + lkg * 4;
#pragma unroll
      for (int r = 0; r < 4; ++r) {
        const int d = qg + r - kg;
        const float pv = (d >= 0) ? s[mf][r] * exp2f((float)d * L2GAMMA) * INV_SQRT_H : 0.0f;
        Plds[(mf * 16 + lkg * 4 + r) * 72 + wid * 16 + lrow] = f2bf(pv);
      }
    }
    __syncthreads();
    // ---- O += P V  (K-dim 64, this wave's h-cols wid*64..+63) ----
#pragma unroll
    for (int ks = 0; ks < 2; ++ks) {
      bf16x8 pa[2];
      pa[0] = *(const bf16x8*)&Plds[(lrow) * 72 + ks * 32 + lk];
      pa[1] = *(const bf16x8*)&Plds[(16 + lrow) * 72 + ks * 32 + lk];
#pragma unroll
      for (int nf = 0; nf < 4; ++nf) {
        const bf16x8 vb = *(const bf16x8*)&Vt[((size_t)b * 256 + wid * 64 + nf * 16 + lrow) * 4096 + kb + ks * 32 + lk];
        oacc[0][nf] = __builtin_amdgcn_mfma_f32_16x16x32_bf16(pa[0], vb, oacc[0][nf], 0, 0, 0);
        oacc[1][nf] = __builtin_amdgcn_mfma_f32_16x16x32_bf16(pa[1], vb, oacc[1][nf], 0, 0, 0);
      }
    }
    __syncthreads();
  }

  // ---- epilogue: fp32 out (B,L,H) ----
#pragma unroll
  for (int mf = 0; mf < 2; ++mf) {
    float* obase = out + ((size_t)b * 4096 + qb + mf * 16 + lkg * 4) * 256 + wid * 64 + lrow;
#pragma unroll
    for (int nf = 0; nf < 4; ++nf)
#pragma unroll
      for (int r = 0; r < 4; ++r)
        obase[(size_t)r * 256 + nf * 16] = oacc[mf][nf][r];
  }
}

extern "C" void kernel_launch(void* const* d_in, const int* in_sizes, int n_in,
                              void* d_out, int out_size, void* d_ws, size_t ws_size,
                              hipStream_t stream) {
  const float* x  = (const float*)d_in[0];
  const float* wq = (const float*)d_in[1];
  const float* wk = (const float*)d_in[2];
  const float* wv = (const float*)d_in[3];
  float* out = (float*)d_out;
  char* ws = (char*)d_ws;
  u16* Xb = (u16*)(ws);                          // 16384*1024*2 = 33,554,432
  u16* Wb = (u16*)(ws + (size_t)33554432);       //   768*1024*2 =  1,572,864
  u16* Qb = (u16*)(ws + (size_t)35127296);       // 16384*256*2  =  8,388,608
  u16* Kb = (u16*)(ws + (size_t)43515904);       //  8,388,608
  u16* Vt = (u16*)(ws + (size_t)51904512);       //  8,388,608  (end 60,293,120)

  hipLaunchKernelGGL(cvt_x_kernel, dim3(2048), dim3(256), 0, stream,
                     (const float4*)x, (u16x4*)Xb, 4194304);
  hipLaunchKernelGGL(cvt_w_kernel, dim3(768), dim3(256), 0, stream,
                     (const float4*)wq, (const float4*)wk, (const float4*)wv, (u16x4*)Wb);
  hipLaunchKernelGGL(qkv_gemm_kernel, dim3(6, 128), dim3(256), 0, stream, Xb, Wb, Qb, Kb, Vt);
  hipLaunchKernelGGL(attn_kernel, dim3(512), dim3(256), 0, stream, Qb, Kb, Vt, out);
}

// Round 3
// 92.435 us; speedup vs baseline: 3.6676x; 1.1412x over previous
//
#include <hip/hip_runtime.h>

typedef unsigned short u16;
typedef __attribute__((ext_vector_type(8))) short bf16x8;
typedef __attribute__((ext_vector_type(4))) float f32x4;
typedef __attribute__((ext_vector_type(4))) unsigned short u16x4;

#define DEVI __device__ __forceinline__

constexpr float L2GAMMA = -0.15200309344504997f; // log2(0.9)
constexpr float INV_SQRT_H = 0.0625f;            // 1/sqrt(256)

DEVI u16 f2bf(float x) {
  union { float f; unsigned u; } v; v.f = x;
  unsigned r = v.u + 0x7FFFu + ((v.u >> 16) & 1u);
  return (u16)(r >> 16);
}

// ---- kernel 0a: x fp32 -> bf16 ------------------------------------------
__global__ void cvt_x_kernel(const float4* __restrict__ src, u16x4* __restrict__ dst, int n4) {
  int stride = gridDim.x * blockDim.x;
  for (int i = blockIdx.x * blockDim.x + threadIdx.x; i < n4; i += stride) {
    float4 v = src[i];
    u16x4 o; o.x = f2bf(v.x); o.y = f2bf(v.y); o.z = f2bf(v.z); o.w = f2bf(v.w);
    dst[i] = o;
  }
}

// ---- kernel 0b: W_Q|W_K|W_V (each 256x1024 fp32) -> Wb[768][1024] bf16 ---
__global__ void cvt_w_kernel(const float4* __restrict__ wq, const float4* __restrict__ wk,
                             const float4* __restrict__ wv, u16x4* __restrict__ dst) {
  int i = blockIdx.x * blockDim.x + threadIdx.x; // 0..196607 (grid exactly covers)
  int w = i >> 16, off = i & 65535;
  const float4* s = (w == 0) ? wq : ((w == 1) ? wk : wv);
  float4 v = s[off];
  u16x4 o; o.x = f2bf(v.x); o.y = f2bf(v.y); o.z = f2bf(v.z); o.w = f2bf(v.w);
  dst[(w << 16) + off] = o;
}

// ---- kernel 1: QKV GEMM  C[16384x768] = Xb[16384x1024] * Wb^T ------------
// 128x128 tile, BK=64, 4 waves. XCD-chunked remap (768 = 8*96) so the 6
// n-tiles sharing an A-panel stay on one XCD (L2-resident A).
// LDS [128][64] u16 (128 B rows) with T2 XOR swizzle cb^=((row&7)<<4),
// applied on the per-lane GLOBAL source (linear gload_lds dest) and on the
// swizzled ds_read address (rule 21: both-sides-or-neither).
__global__ __launch_bounds__(256) void qkv_gemm_kernel(const u16* __restrict__ Xb, const u16* __restrict__ Wb,
                                                       u16* __restrict__ Qb, u16* __restrict__ Kb,
                                                       u16* __restrict__ Vt) {
  __shared__ u16 Alds[128 * 64];
  __shared__ u16 Blds[128 * 64];
  const int linear = blockIdx.x + blockIdx.y * 6;       // 0..767
  const int rl = (linear & 7) * 96 + (linear >> 3);     // XCD-chunked bijection
  const int nt = rl % 6;
  const int m0 = (rl / 6) * 128;
  const int n0 = nt * 128;
  const int tid = threadIdx.x;
  const int wid = tid >> 6, lane = tid & 63;
  const int wm = wid >> 1, wn = wid & 1;
  const int lrow = lane & 15, lkg = lane >> 4;
  const int srow = lane >> 3;                           // staging: row within 8-row chunk
  const int scol = ((lane & 7) ^ srow) << 3;            // staging: u16 col, inverse-swizzled

  f32x4 acc[4][4] = {};

  for (int kt = 0; kt < 16; ++kt) {
    const int k0 = kt * 64;
#pragma unroll
    for (int r = 0; r < 4; ++r) {
      const int chunk = wid * 4 + r;                    // 0..15, wave-uniform
      const int row = chunk * 8 + srow;
      const u16* gA = Xb + (size_t)(m0 + row) * 1024 + k0 + scol;
      const u16* gB = Wb + (size_t)(n0 + row) * 1024 + k0 + scol;
      __builtin_amdgcn_global_load_lds((const __attribute__((address_space(1))) void*)gA,
                                       (__attribute__((address_space(3))) void*)&Alds[chunk * 512], 16, 0, 0);
      __builtin_amdgcn_global_load_lds((const __attribute__((address_space(1))) void*)gB,
                                       (__attribute__((address_space(3))) void*)&Blds[chunk * 512], 16, 0, 0);
    }
    __syncthreads();
#pragma unroll
    for (int kk = 0; kk < 2; ++kk) {
      bf16x8 a[4], b[4];
      const int sw = ((kk * 4 + lkg) ^ (lrow & 7)) << 3;  // swizzled k-slot (u16)
#pragma unroll
      for (int mf = 0; mf < 4; ++mf) a[mf] = *(const bf16x8*)&Alds[(wm * 64 + mf * 16 + lrow) * 64 + sw];
#pragma unroll
      for (int nf = 0; nf < 4; ++nf) b[nf] = *(const bf16x8*)&Blds[(wn * 64 + nf * 16 + lrow) * 64 + sw];
#pragma unroll
      for (int mf = 0; mf < 4; ++mf)
#pragma unroll
        for (int nf = 0; nf < 4; ++nf)
          acc[mf][nf] = __builtin_amdgcn_mfma_f32_16x16x32_bf16(a[mf], b[nf], acc[mf][nf], 0, 0, 0);
    }
    __syncthreads();
  }

  const int rbase = lkg * 4;
  if (nt < 4) {
    u16* Dst = (nt < 2) ? Qb : Kb;
    const int cb = (nt < 2) ? n0 : (n0 - 256);
#pragma unroll
    for (int mf = 0; mf < 4; ++mf)
#pragma unroll
      for (int nf = 0; nf < 4; ++nf) {
        const int gm = m0 + wm * 64 + mf * 16 + rbase;
        const int c = cb + wn * 64 + nf * 16 + lrow;
#pragma unroll
        for (int r = 0; r < 4; ++r) Dst[(size_t)(gm + r) * 256 + c] = f2bf(acc[mf][nf][r]);
      }
  } else {
#pragma unroll
    for (int mf = 0; mf < 4; ++mf)
#pragma unroll
      for (int nf = 0; nf < 4; ++nf) {
        const int gm = m0 + wm * 64 + mf * 16 + rbase;
        const int h = n0 - 512 + wn * 64 + nf * 16 + lrow;
        const int bb = gm >> 12, l = gm & 4095;
        u16x4 pk;
        pk.x = f2bf(acc[mf][nf][0]); pk.y = f2bf(acc[mf][nf][1]);
        pk.z = f2bf(acc[mf][nf][2]); pk.w = f2bf(acc[mf][nf][3]);
        *(u16x4*)&Vt[((size_t)bb * 256 + h) * 4096 + l] = pk;
      }
  }
}

// ---- kernel 2: WINDOWED decay attention ----------------------------------
// gamma^320 ~ 2.5e-15 => keys older than the aligned 256..319 window are
// numerically zero in fp32. QB=32 rows/WG, KB=64, 4 waves (256 thr).
__global__ __launch_bounds__(256) void attn_kernel(const u16* __restrict__ Qb, const u16* __restrict__ Kb,
                                                   const u16* __restrict__ Vt, float* __restrict__ out) {
  __shared__ u16 Plds[32 * 72];
  const int raw = blockIdx.x;                 // 0..511
  const int aid = (raw & 7) * 64 + (raw >> 3);  // XCD-chunked
  const int b = aid >> 7;                     // 0..3
  const int qt = aid & 127;                   // 0..127
  const int qb = qt * 32;
  const int tid = threadIdx.x;
  const int wid = tid >> 6, lane = tid & 63;
  const int lrow = lane & 15, lkg = lane >> 4, lk = lkg * 8;
  const size_t bQK = (size_t)b * 4096 * 256;

  bf16x8 qf[2][8];
#pragma unroll
  for (int mf = 0; mf < 2; ++mf) {
    const u16* Qrow = Qb + bQK + (size_t)(qb + mf * 16 + lrow) * 256;
#pragma unroll
    for (int kf = 0; kf < 8; ++kf) qf[mf][kf] = *(const bf16x8*)&Qrow[kf * 32 + lk];
  }

  int kstart = qb - 256; if (kstart < 0) kstart = 0; kstart &= ~63;
  const int njt = (qb + 32 - kstart + 63) >> 6;

  f32x4 oacc[2][4] = {};

  for (int jt = 0; jt < njt; ++jt) {
    const int kb = kstart + jt * 64;
    f32x4 s[2] = {};
    const u16* Krow = Kb + bQK + (size_t)(kb + wid * 16 + lrow) * 256;
#pragma unroll
    for (int kf = 0; kf < 8; ++kf) {
      const bf16x8 kfr = *(const bf16x8*)&Krow[kf * 32 + lk];
      s[0] = __builtin_amdgcn_mfma_f32_16x16x32_bf16(qf[0][kf], kfr, s[0], 0, 0, 0);
      s[1] = __builtin_amdgcn_mfma_f32_16x16x32_bf16(qf[1][kf], kfr, s[1], 0, 0, 0);
    }
    const int kg = kb + wid * 16 + lrow;
#pragma unroll
    for (int mf = 0; mf < 2; ++mf) {
      const int qg = qb + mf * 16 + lkg * 4;
#pragma unroll
      for (int r = 0; r < 4; ++r) {
        const int d = qg + r - kg;
        const float pv = (d >= 0) ? s[mf][r] * exp2f((float)d * L2GAMMA) * INV_SQRT_H : 0.0f;
        Plds[(mf * 16 + lkg * 4 + r) * 72 + wid * 16 + lrow] = f2bf(pv);
      }
    }
    __syncthreads();
#pragma unroll
    for (int ks = 0; ks < 2; ++ks) {
      bf16x8 pa[2];
      pa[0] = *(const bf16x8*)&Plds[(lrow) * 72 + ks * 32 + lk];
      pa[1] = *(const bf16x8*)&Plds[(16 + lrow) * 72 + ks * 32 + lk];
#pragma unroll
      for (int nf = 0; nf < 4; ++nf) {
        const bf16x8 vb = *(const bf16x8*)&Vt[((size_t)b * 256 + wid * 64 + nf * 16 + lrow) * 4096 + kb + ks * 32 + lk];
        oacc[0][nf] = __builtin_amdgcn_mfma_f32_16x16x32_bf16(pa[0], vb, oacc[0][nf], 0, 0, 0);
        oacc[1][nf] = __builtin_amdgcn_mfma_f32_16x16x32_bf16(pa[1], vb, oacc[1][nf], 0, 0, 0);
      }
    }
    __syncthreads();
  }

#pragma unroll
  for (int mf = 0; mf < 2; ++mf) {
    float* obase = out + ((size_t)b * 4096 + qb + mf * 16 + lkg * 4) * 256 + wid * 64 + lrow;
#pragma unroll
    for (int nf = 0; nf < 4; ++nf)
#pragma unroll
      for (int r = 0; r < 4; ++r)
        obase[(size_t)r * 256 + nf * 16] = oacc[mf][nf][r];
  }
}

extern "C" void kernel_launch(void* const* d_in, const int* in_sizes, int n_in,
                              void* d_out, int out_size, void* d_ws, size_t ws_size,
                              hipStream_t stream) {
  const float* x  = (const float*)d_in[0];
  const float* wq = (const float*)d_in[1];
  const float* wk = (const float*)d_in[2];
  const float* wv = (const float*)d_in[3];
  float* out = (float*)d_out;
  char* ws = (char*)d_ws;
  u16* Xb = (u16*)(ws);                          // 16384*1024*2 = 33,554,432
  u16* Wb = (u16*)(ws + (size_t)33554432);       //   768*1024*2 =  1,572,864
  u16* Qb = (u16*)(ws + (size_t)35127296);       // 16384*256*2  =  8,388,608
  u16* Kb = (u16*)(ws + (size_t)43515904);       //  8,388,608
  u16* Vt = (u16*)(ws + (size_t)51904512);       //  8,388,608  (end 60,293,120)

  hipLaunchKernelGGL(cvt_x_kernel, dim3(2048), dim3(256), 0, stream,
                     (const float4*)x, (u16x4*)Xb, 4194304);
  hipLaunchKernelGGL(cvt_w_kernel, dim3(768), dim3(256), 0, stream,
                     (const float4*)wq, (const float4*)wk, (const float4*)wv, (u16x4*)Wb);
  hipLaunchKernelGGL(qkv_gemm_kernel, dim3(6, 128), dim3(256), 0, stream, Xb, Wb, Qb, Kb, Vt);
  hipLaunchKernelGGL(attn_kernel, dim3(512), dim3(256), 0, stream, Qb, Kb, Vt, out);
}

// Round 4
// 88.460 us; speedup vs baseline: 3.8324x; 1.0449x over previous
//
#include <hip/hip_runtime.h>

typedef unsigned short u16;
typedef unsigned int u32;
typedef __attribute__((ext_vector_type(8))) short bf16x8;
typedef __attribute__((ext_vector_type(4))) float f32x4;
typedef __attribute__((ext_vector_type(4))) unsigned short u16x4;

#define DEVI __device__ __forceinline__

constexpr float L2GAMMA = -0.15200309344504997f; // log2(0.9)
constexpr float INV_SQRT_H = 0.0625f;            // 1/sqrt(256)

DEVI u16 f2bf(float x) {
  union { float f; unsigned u; } v; v.f = x;
  unsigned r = v.u + 0x7FFFu + ((v.u >> 16) & 1u);
  return (u16)(r >> 16);
}

// pack two floats -> two bf16 (round-half-up) in one u32 via v_perm
DEVI u32 pack2bf(float f0, float f1) {
  u32 u0 = __float_as_uint(f0) + 0x8000u;
  u32 u1 = __float_as_uint(f1) + 0x8000u;
  return __builtin_amdgcn_perm(u1, u0, 0x07060302u); // [r1.hi16 : r0.hi16]
}

// ---- kernel 0: W_Q|W_K|W_V (each 256x1024 fp32) -> Wb[768][1024] bf16 ----
__global__ void cvt_w_kernel(const float4* __restrict__ wq, const float4* __restrict__ wk,
                             const float4* __restrict__ wv, u16x4* __restrict__ dst) {
  int i = blockIdx.x * blockDim.x + threadIdx.x; // 0..196607 (grid exactly covers)
  int w = i >> 16, off = i & 65535;
  const float4* s = (w == 0) ? wq : ((w == 1) ? wk : wv);
  float4 v = s[off];
  u16x4 o; o.x = f2bf(v.x); o.y = f2bf(v.y); o.z = f2bf(v.z); o.w = f2bf(v.w);
  dst[(w << 16) + off] = o;
}

// ---- kernel 1: fused QKV GEMM  C[16384x768] = x[16384x1024](fp32) * Wb^T --
// 128x128 tile, BK=64, 4 waves, 2-phase double-buffered pipeline:
//   issue loads(kt+1) -> compute(kt) -> cvt+write A(kt+1) -> wait -> barrier
// A: fp32 reg-staged, converted to bf16 in-flight, ds_write with XOR swizzle.
// B: global_load_lds with inverse-swizzled global source (linear LDS dest).
// XCD-chunked WG remap (768 = 8*96) keeps A-panel reuse on one XCD's L2.
__global__ __launch_bounds__(256, 2) void qkv_gemm_kernel(const float* __restrict__ Xf, const u16* __restrict__ Wb,
                                                          u16* __restrict__ Qb, u16* __restrict__ Kb,
                                                          u16* __restrict__ Vt) {
  __shared__ u16 Alds[2][128 * 64];
  __shared__ u16 Blds[2][128 * 64];
  const int linear = blockIdx.x + blockIdx.y * 6;       // 0..767
  const int rl = (linear & 7) * 96 + (linear >> 3);     // XCD-chunked bijection
  const int nt = rl % 6;
  const int m0 = (rl / 6) * 128;
  const int n0 = nt * 128;
  const int tid = threadIdx.x;
  const int wid = tid >> 6, lane = tid & 63;
  const int wm = wid >> 1, wn = wid & 1;
  const int lrow = lane & 15, lkg = lane >> 4;
  const int l8 = lane >> 3, l7 = lane & 7;
  const int scol = (l7 ^ l8) << 3;                      // B staging col (u16), inverse-swizzled
  const int acu = ((l7 << 3) ^ (l8 << 3));              // A write col (u16), swizzled (r&7 == l8)

  // A staging: lane covers rows wid*32 + p*8 + l8, fp32 cols l7*8 .. +7
  const float* agbase = Xf + (size_t)(m0 + wid * 32 + l8) * 1024 + l7 * 8;
  float4 areg[8];

#define LOADA(KT) do { const float* g_ = agbase + (KT) * 64; \
  _Pragma("unroll") for (int p_ = 0; p_ < 4; ++p_) { \
    areg[2*p_]   = *(const float4*)(g_ + (size_t)p_ * 8 * 1024); \
    areg[2*p_+1] = *(const float4*)(g_ + (size_t)p_ * 8 * 1024 + 4); } } while (0)

#define STAGEB(KT, BUF) do { const int k0_ = (KT) * 64; \
  _Pragma("unroll") for (int r_ = 0; r_ < 4; ++r_) { \
    const int chunk_ = wid * 4 + r_; \
    const u16* gB_ = Wb + (size_t)(n0 + chunk_ * 8 + l8) * 1024 + k0_ + scol; \
    __builtin_amdgcn_global_load_lds((const __attribute__((address_space(1))) void*)gB_, \
        (__attribute__((address_space(3))) void*)&Blds[BUF][chunk_ * 512], 16, 0, 0); } } while (0)

#define CVTWRITE(BUF) do { \
  _Pragma("unroll") for (int p_ = 0; p_ < 4; ++p_) { \
    const int r_ = wid * 32 + p_ * 8 + l8; \
    u32 w0 = pack2bf(areg[2*p_].x, areg[2*p_].y); \
    u32 w1 = pack2bf(areg[2*p_].z, areg[2*p_].w); \
    u32 w2 = pack2bf(areg[2*p_+1].x, areg[2*p_+1].y); \
    u32 w3 = pack2bf(areg[2*p_+1].z, areg[2*p_+1].w); \
    uint4 pk_; pk_.x = w0; pk_.y = w1; pk_.z = w2; pk_.w = w3; \
    *(uint4*)&Alds[BUF][r_ * 64 + acu] = pk_; } } while (0)

  f32x4 acc[4][4] = {};

  // ---- prologue: tile 0 ----
  LOADA(0);
  STAGEB(0, 0);
  CVTWRITE(0);
  asm volatile("s_waitcnt vmcnt(0) lgkmcnt(0)" ::: "memory");
  __builtin_amdgcn_s_barrier();

  int cur = 0;
  for (int kt = 0; kt < 16; ++kt) {
    const int nxt = cur ^ 1;
    if (kt < 15) { LOADA(kt + 1); STAGEB(kt + 1, nxt); }
    __builtin_amdgcn_sched_barrier(0);
    // ---- compute tile kt from buf cur ----
    {
      const u16* Ab = Alds[cur];
      const u16* Bb = Blds[cur];
#pragma unroll
      for (int kk = 0; kk < 2; ++kk) {
        bf16x8 a[4], b[4];
        const int sw = ((kk * 4 + lkg) ^ (lrow & 7)) << 3;
#pragma unroll
        for (int mf = 0; mf < 4; ++mf) a[mf] = *(const bf16x8*)&Ab[(wm * 64 + mf * 16 + lrow) * 64 + sw];
#pragma unroll
        for (int nf = 0; nf < 4; ++nf) b[nf] = *(const bf16x8*)&Bb[(wn * 64 + nf * 16 + lrow) * 64 + sw];
#pragma unroll
        for (int mf = 0; mf < 4; ++mf)
#pragma unroll
          for (int nf = 0; nf < 4; ++nf)
            acc[mf][nf] = __builtin_amdgcn_mfma_f32_16x16x32_bf16(a[mf], b[nf], acc[mf][nf], 0, 0, 0);
      }
    }
    __builtin_amdgcn_sched_barrier(0);
    if (kt < 15) {
      CVTWRITE(nxt);
      asm volatile("s_waitcnt vmcnt(0) lgkmcnt(0)" ::: "memory");
      __builtin_amdgcn_s_barrier();
    }
    cur = nxt;
  }

  // ---- epilogue ----
  const int rbase = lkg * 4;
  if (nt < 4) {
    u16* Dst = (nt < 2) ? Qb : Kb;
    const int cb = (nt < 2) ? n0 : (n0 - 256);
#pragma unroll
    for (int mf = 0; mf < 4; ++mf)
#pragma unroll
      for (int nf = 0; nf < 4; ++nf) {
        const int gm = m0 + wm * 64 + mf * 16 + rbase;
        const int c = cb + wn * 64 + nf * 16 + lrow;
#pragma unroll
        for (int r = 0; r < 4; ++r) Dst[(size_t)(gm + r) * 256 + c] = f2bf(acc[mf][nf][r]);
      }
  } else {
#pragma unroll
    for (int mf = 0; mf < 4; ++mf)
#pragma unroll
      for (int nf = 0; nf < 4; ++nf) {
        const int gm = m0 + wm * 64 + mf * 16 + rbase;
        const int h = n0 - 512 + wn * 64 + nf * 16 + lrow;
        const int bb = gm >> 12, l = gm & 4095;
        u16x4 pk;
        pk.x = f2bf(acc[mf][nf][0]); pk.y = f2bf(acc[mf][nf][1]);
        pk.z = f2bf(acc[mf][nf][2]); pk.w = f2bf(acc[mf][nf][3]);
        *(u16x4*)&Vt[((size_t)bb * 256 + h) * 4096 + l] = pk;
      }
  }
}

// ---- kernel 2: WINDOWED decay attention ----------------------------------
// gamma^320 ~ 2.5e-15 => keys older than the aligned 256..319 window are
// numerically zero in fp32. QB=32 rows/WG, KB=64, 4 waves (256 thr).
__global__ __launch_bounds__(256) void attn_kernel(const u16* __restrict__ Qb, const u16* __restrict__ Kb,
                                                   const u16* __restrict__ Vt, float* __restrict__ out) {
  __shared__ u16 Plds[32 * 72];
  const int raw = blockIdx.x;                 // 0..511
  const int aid = (raw & 7) * 64 + (raw >> 3);  // XCD-chunked
  const int b = aid >> 7;                     // 0..3
  const int qt = aid & 127;                   // 0..127
  const int qb = qt * 32;
  const int tid = threadIdx.x;
  const int wid = tid >> 6, lane = tid & 63;
  const int lrow = lane & 15, lkg = lane >> 4, lk = lkg * 8;
  const size_t bQK = (size_t)b * 4096 * 256;

  bf16x8 qf[2][8];
#pragma unroll
  for (int mf = 0; mf < 2; ++mf) {
    const u16* Qrow = Qb + bQK + (size_t)(qb + mf * 16 + lrow) * 256;
#pragma unroll
    for (int kf = 0; kf < 8; ++kf) qf[mf][kf] = *(const bf16x8*)&Qrow[kf * 32 + lk];
  }

  int kstart = qb - 256; if (kstart < 0) kstart = 0; kstart &= ~63;
  const int njt = (qb + 32 - kstart + 63) >> 6;

  f32x4 oacc[2][4] = {};

  for (int jt = 0; jt < njt; ++jt) {
    const int kb = kstart + jt * 64;
    f32x4 s[2] = {};
    const u16* Krow = Kb + bQK + (size_t)(kb + wid * 16 + lrow) * 256;
#pragma unroll
    for (int kf = 0; kf < 8; ++kf) {
      const bf16x8 kfr = *(const bf16x8*)&Krow[kf * 32 + lk];
      s[0] = __builtin_amdgcn_mfma_f32_16x16x32_bf16(qf[0][kf], kfr, s[0], 0, 0, 0);
      s[1] = __builtin_amdgcn_mfma_f32_16x16x32_bf16(qf[1][kf], kfr, s[1], 0, 0, 0);
    }
    const int kg = kb + wid * 16 + lrow;
#pragma unroll
    for (int mf = 0; mf < 2; ++mf) {
      const int qg = qb + mf * 16 + lkg * 4;
#pragma unroll
      for (int r = 0; r < 4; ++r) {
        const int d = qg + r - kg;
        const float pv = (d >= 0) ? s[mf][r] * exp2f((float)d * L2GAMMA) * INV_SQRT_H : 0.0f;
        Plds[(mf * 16 + lkg * 4 + r) * 72 + wid * 16 + lrow] = f2bf(pv);
      }
    }
    __syncthreads();
#pragma unroll
    for (int ks = 0; ks < 2; ++ks) {
      bf16x8 pa[2];
      pa[0] = *(const bf16x8*)&Plds[(lrow) * 72 + ks * 32 + lk];
      pa[1] = *(const bf16x8*)&Plds[(16 + lrow) * 72 + ks * 32 + lk];
#pragma unroll
      for (int nf = 0; nf < 4; ++nf) {
        const bf16x8 vb = *(const bf16x8*)&Vt[((size_t)b * 256 + wid * 64 + nf * 16 + lrow) * 4096 + kb + ks * 32 + lk];
        oacc[0][nf] = __builtin_amdgcn_mfma_f32_16x16x32_bf16(pa[0], vb, oacc[0][nf], 0, 0, 0);
        oacc[1][nf] = __builtin_amdgcn_mfma_f32_16x16x32_bf16(pa[1], vb, oacc[1][nf], 0, 0, 0);
      }
    }
    __syncthreads();
  }

#pragma unroll
  for (int mf = 0; mf < 2; ++mf) {
    float* obase = out + ((size_t)b * 4096 + qb + mf * 16 + lkg * 4) * 256 + wid * 64 + lrow;
#pragma unroll
    for (int nf = 0; nf < 4; ++nf)
#pragma unroll
      for (int r = 0; r < 4; ++r)
        obase[(size_t)r * 256 + nf * 16] = oacc[mf][nf][r];
  }
}

extern "C" void kernel_launch(void* const* d_in, const int* in_sizes, int n_in,
                              void* d_out, int out_size, void* d_ws, size_t ws_size,
                              hipStream_t stream) {
  const float* x  = (const float*)d_in[0];
  const float* wq = (const float*)d_in[1];
  const float* wk = (const float*)d_in[2];
  const float* wv = (const float*)d_in[3];
  float* out = (float*)d_out;
  char* ws = (char*)d_ws;
  u16* Wb = (u16*)(ws);                          //   768*1024*2 = 1,572,864
  u16* Qb = (u16*)(ws + (size_t)1572864);        // 16384*256*2  = 8,388,608
  u16* Kb = (u16*)(ws + (size_t)9961472);        //  8,388,608
  u16* Vt = (u16*)(ws + (size_t)18350080);       //  8,388,608  (end 26,738,688)

  hipLaunchKernelGGL(cvt_w_kernel, dim3(768), dim3(256), 0, stream,
                     (const float4*)wq, (const float4*)wk, (const float4*)wv, (u16x4*)Wb);
  hipLaunchKernelGGL(qkv_gemm_kernel, dim3(6, 128), dim3(256), 0, stream, x, Wb, Qb, Kb, Vt);
  hipLaunchKernelGGL(attn_kernel, dim3(512), dim3(256), 0, stream, Qb, Kb, Vt, out);
}

// Round 5
// 84.576 us; speedup vs baseline: 4.0084x; 1.0459x over previous
//
#include <hip/hip_runtime.h>

typedef unsigned short u16;
typedef unsigned int u32;
typedef __attribute__((ext_vector_type(8))) short bf16x8;
typedef __attribute__((ext_vector_type(4))) float f32x4;
typedef __attribute__((ext_vector_type(4))) unsigned short u16x4;

#define DEVI __device__ __forceinline__

constexpr float L2GAMMA = -0.15200309344504997f; // log2(0.9)
constexpr float INV_SQRT_H = 0.0625f;            // 1/sqrt(256)

DEVI u16 f2bf(float x) {
  union { float f; unsigned u; } v; v.f = x;
  unsigned r = v.u + 0x7FFFu + ((v.u >> 16) & 1u);
  return (u16)(r >> 16);
}

// pack two floats -> two bf16 (round-half-up) in one u32 via v_perm
DEVI u32 pack2bf(float f0, float f1) {
  u32 u0 = __float_as_uint(f0) + 0x8000u;
  u32 u1 = __float_as_uint(f1) + 0x8000u;
  return __builtin_amdgcn_perm(u1, u0, 0x07060302u); // [f1.hi16 : f0.hi16]
}

// ---- kernel 0: W_Q|W_K|W_V (each 256x1024 fp32) -> Wb[768][1024] bf16 ----
__global__ void cvt_w_kernel(const float4* __restrict__ wq, const float4* __restrict__ wk,
                             const float4* __restrict__ wv, u16x4* __restrict__ dst) {
  int i = blockIdx.x * blockDim.x + threadIdx.x; // 0..196607 (grid exactly covers)
  int w = i >> 16, off = i & 65535;
  const float4* s = (w == 0) ? wq : ((w == 1) ? wk : wv);
  float4 v = s[off];
  u16x4 o; o.x = f2bf(v.x); o.y = f2bf(v.y); o.z = f2bf(v.z); o.w = f2bf(v.w);
  dst[(w << 16) + off] = o;
}

// ---- kernel 1: fused QKV GEMM  C[16384x768] = x[16384x1024](fp32)*Wb^T ---
// BM=256 BN=192 BK=32, 512 thr (8 waves, 4Mx2N; wave tile 64x96).
// Grid 256 = 64 m-tiles x 4 n-tiles = 1 WG/CU. xcd=bid&7 -> 8 m-panels/XCD.
// Double-buffered LDS, ONE __syncthreads per K-tile:
//   issue A-reg loads(t+1) + B gload_lds(t+1 -> p^1); ds_read frags(p);
//   24 MFMA; cvt+ds_write A(t+1 -> p^1); sync.
// Swizzle: 64B rows, 4 slots of 16B; slot' = slot ^ k(row),
// k(row) = (row&3)^((row>>2)&3)  => all LDS access <=2-way (free).
__global__ __launch_bounds__(512, 2) void qkv_gemm_kernel(const float* __restrict__ Xf, const u16* __restrict__ Wb,
                                                          u16* __restrict__ Qb, u16* __restrict__ Kb,
                                                          u16* __restrict__ Vt) {
  __shared__ u16 Alds[2][256 * 32];
  __shared__ u16 Blds[2][192 * 32];
  const int bid = blockIdx.x;                 // 0..255
  const int xcd = bid & 7, seq = bid >> 3;    // 32 WGs per XCD
  const int m0 = (xcd * 8 + (seq >> 2)) * 256;
  const int n0 = (seq & 3) * 192;
  const int tid = threadIdx.x;
  const int wid = tid >> 6, lane = tid & 63;
  const int wm = wid >> 1, wn = wid & 1;      // 4Mx2N wave grid
  const int lrow = lane & 15, lkg = lane >> 4;
  const int kidx = (lrow & 3) ^ ((lrow >> 2) & 3);          // frag-read swizzle key
  const int kw = ((tid >> 2) & 3) ^ ((tid >> 4) & 3);       // A-write key
  const int kb = ((lane >> 2) & 3) ^ ((lane >> 4) & 3);     // B-stage key

  // A: thread covers rows {tid>>2, 128+(tid>>2)}, fp32 cols (tid&3)*8..+7
  const float* agbase = Xf + (size_t)(m0 + (tid >> 2)) * 1024 + (tid & 3) * 8;
  const int awr0 = (tid >> 2) * 32 + (((tid & 3) ^ kw) << 3);
  const int awr1 = awr0 + 128 * 32;
  float4 ar[4];

  // B: chunk = wid (+ chunk 8+wid for wid<4); lane covers row chunk*16+(l>>2)
  const u16* bgbase = Wb + (size_t)(n0 + wid * 16 + (lane >> 2)) * 1024 + (((lane & 3) ^ kb) << 3);

#define LOADA(KT) do { const float* g_ = agbase + (KT) * 32; \
  ar[0] = *(const float4*)(g_); \
  ar[1] = *(const float4*)(g_ + 4); \
  ar[2] = *(const float4*)(g_ + (size_t)128 * 1024); \
  ar[3] = *(const float4*)(g_ + (size_t)128 * 1024 + 4); } while (0)

#define STAGEB(KT, BUF) do { const u16* gB_ = bgbase + (KT) * 32; \
  __builtin_amdgcn_global_load_lds((const __attribute__((address_space(1))) void*)gB_, \
      (__attribute__((address_space(3))) void*)&Blds[BUF][wid * 512], 16, 0, 0); \
  if (wid < 4) { \
    __builtin_amdgcn_global_load_lds((const __attribute__((address_space(1))) void*)(gB_ + (size_t)128 * 1024), \
        (__attribute__((address_space(3))) void*)&Blds[BUF][(8 + wid) * 512], 16, 0, 0); } } while (0)

#define CVTWRITE(BUF) do { \
  uint4 p0_, p1_; \
  p0_.x = pack2bf(ar[0].x, ar[0].y); p0_.y = pack2bf(ar[0].z, ar[0].w); \
  p0_.z = pack2bf(ar[1].x, ar[1].y); p0_.w = pack2bf(ar[1].z, ar[1].w); \
  p1_.x = pack2bf(ar[2].x, ar[2].y); p1_.y = pack2bf(ar[2].z, ar[2].w); \
  p1_.z = pack2bf(ar[3].x, ar[3].y); p1_.w = pack2bf(ar[3].z, ar[3].w); \
  *(uint4*)&Alds[BUF][awr0] = p0_; \
  *(uint4*)&Alds[BUF][awr1] = p1_; } while (0)

  f32x4 acc[4][6] = {};

  // ---- prologue: tile 0 ----
  LOADA(0);
  STAGEB(0, 0);
  CVTWRITE(0);
  __syncthreads();

  for (int kt = 0; kt < 32; ++kt) {
    const int p = kt & 1;
    if (kt < 31) { LOADA(kt + 1); STAGEB(kt + 1, p ^ 1); }
    const u16* Ab = Alds[p];
    const u16* Bb = Blds[p];
    bf16x8 af[4], bfr[6];
    const int sw = (lkg ^ kidx) << 3;
#pragma unroll
    for (int mf = 0; mf < 4; ++mf) af[mf] = *(const bf16x8*)&Ab[(wm * 64 + mf * 16 + lrow) * 32 + sw];
#pragma unroll
    for (int nf = 0; nf < 6; ++nf) bfr[nf] = *(const bf16x8*)&Bb[(wn * 96 + nf * 16 + lrow) * 32 + sw];
    __builtin_amdgcn_s_setprio(1);
#pragma unroll
    for (int mf = 0; mf < 4; ++mf)
#pragma unroll
      for (int nf = 0; nf < 6; ++nf)
        acc[mf][nf] = __builtin_amdgcn_mfma_f32_16x16x32_bf16(af[mf], bfr[nf], acc[mf][nf], 0, 0, 0);
    __builtin_amdgcn_s_setprio(0);
    if (kt < 31) CVTWRITE(p ^ 1);
    __syncthreads();
  }

  // ---- epilogue: route cols to Q / K / V(transposed) ----
#pragma unroll
  for (int mf = 0; mf < 4; ++mf)
#pragma unroll
    for (int nf = 0; nf < 6; ++nf) {
      const int gm = m0 + wm * 64 + mf * 16 + lkg * 4;
      const int c = n0 + wn * 96 + nf * 16 + lrow;      // region uniform per frag
      if (c < 512) {
        u16* Dst = (c < 256) ? Qb : Kb;
        const int cc = c & 255;
#pragma unroll
        for (int r = 0; r < 4; ++r) Dst[(size_t)(gm + r) * 256 + cc] = f2bf(acc[mf][nf][r]);
      } else {
        const int h = c - 512;
        const int bb = gm >> 12, l = gm & 4095;
        u16x4 pk;
        pk.x = f2bf(acc[mf][nf][0]); pk.y = f2bf(acc[mf][nf][1]);
        pk.z = f2bf(acc[mf][nf][2]); pk.w = f2bf(acc[mf][nf][3]);
        *(u16x4*)&Vt[((size_t)bb * 256 + h) * 4096 + l] = pk;
      }
    }
}

// ---- kernel 2: WINDOWED decay attention ----------------------------------
// gamma^320 ~ 2.5e-15 => keys older than the aligned 256..319 window are
// numerically zero in fp32. QB=32 rows/WG, KB=64, 4 waves (256 thr).
__global__ __launch_bounds__(256) void attn_kernel(const u16* __restrict__ Qb, const u16* __restrict__ Kb,
                                                   const u16* __restrict__ Vt, float* __restrict__ out) {
  __shared__ u16 Plds[32 * 72];
  const int raw = blockIdx.x;                 // 0..511
  const int aid = (raw & 7) * 64 + (raw >> 3);  // XCD-chunked
  const int b = aid >> 7;                     // 0..3
  const int qt = aid & 127;                   // 0..127
  const int qb = qt * 32;
  const int tid = threadIdx.x;
  const int wid = tid >> 6, lane = tid & 63;
  const int lrow = lane & 15, lkg = lane >> 4, lk = lkg * 8;
  const size_t bQK = (size_t)b * 4096 * 256;

  bf16x8 qf[2][8];
#pragma unroll
  for (int mf = 0; mf < 2; ++mf) {
    const u16* Qrow = Qb + bQK + (size_t)(qb + mf * 16 + lrow) * 256;
#pragma unroll
    for (int kf = 0; kf < 8; ++kf) qf[mf][kf] = *(const bf16x8*)&Qrow[kf * 32 + lk];
  }

  int kstart = qb - 256; if (kstart < 0) kstart = 0; kstart &= ~63;
  const int njt = (qb + 32 - kstart + 63) >> 6;

  f32x4 oacc[2][4] = {};

  for (int jt = 0; jt < njt; ++jt) {
    const int kb = kstart + jt * 64;
    f32x4 s[2] = {};
    const u16* Krow = Kb + bQK + (size_t)(kb + wid * 16 + lrow) * 256;
#pragma unroll
    for (int kf = 0; kf < 8; ++kf) {
      const bf16x8 kfr = *(const bf16x8*)&Krow[kf * 32 + lk];
      s[0] = __builtin_amdgcn_mfma_f32_16x16x32_bf16(qf[0][kf], kfr, s[0], 0, 0, 0);
      s[1] = __builtin_amdgcn_mfma_f32_16x16x32_bf16(qf[1][kf], kfr, s[1], 0, 0, 0);
    }
    const int kg = kb + wid * 16 + lrow;
#pragma unroll
    for (int mf = 0; mf < 2; ++mf) {
      const int qg = qb + mf * 16 + lkg * 4;
#pragma unroll
      for (int r = 0; r < 4; ++r) {
        const int d = qg + r - kg;
        const float pv = (d >= 0) ? s[mf][r] * exp2f((float)d * L2GAMMA) * INV_SQRT_H : 0.0f;
        Plds[(mf * 16 + lkg * 4 + r) * 72 + wid * 16 + lrow] = f2bf(pv);
      }
    }
    __syncthreads();
#pragma unroll
    for (int ks = 0; ks < 2; ++ks) {
      bf16x8 pa[2];
      pa[0] = *(const bf16x8*)&Plds[(lrow) * 72 + ks * 32 + lk];
      pa[1] = *(const bf16x8*)&Plds[(16 + lrow) * 72 + ks * 32 + lk];
#pragma unroll
      for (int nf = 0; nf < 4; ++nf) {
        const bf16x8 vb = *(const bf16x8*)&Vt[((size_t)b * 256 + wid * 64 + nf * 16 + lrow) * 4096 + kb + ks * 32 + lk];
        oacc[0][nf] = __builtin_amdgcn_mfma_f32_16x16x32_bf16(pa[0], vb, oacc[0][nf], 0, 0, 0);
        oacc[1][nf] = __builtin_amdgcn_mfma_f32_16x16x32_bf16(pa[1], vb, oacc[1][nf], 0, 0, 0);
      }
    }
    __syncthreads();
  }

#pragma unroll
  for (int mf = 0; mf < 2; ++mf) {
    float* obase = out + ((size_t)b * 4096 + qb + mf * 16 + lkg * 4) * 256 + wid * 64 + lrow;
#pragma unroll
    for (int nf = 0; nf < 4; ++nf)
#pragma unroll
      for (int r = 0; r < 4; ++r)
        obase[(size_t)r * 256 + nf * 16] = oacc[mf][nf][r];
  }
}

extern "C" void kernel_launch(void* const* d_in, const int* in_sizes, int n_in,
                              void* d_out, int out_size, void* d_ws, size_t ws_size,
                              hipStream_t stream) {
  const float* x  = (const float*)d_in[0];
  const float* wq = (const float*)d_in[1];
  const float* wk = (const float*)d_in[2];
  const float* wv = (const float*)d_in[3];
  float* out = (float*)d_out;
  char* ws = (char*)d_ws;
  u16* Wb = (u16*)(ws);                          //   768*1024*2 = 1,572,864
  u16* Qb = (u16*)(ws + (size_t)1572864);        // 16384*256*2  = 8,388,608
  u16* Kb = (u16*)(ws + (size_t)9961472);        //  8,388,608
  u16* Vt = (u16*)(ws + (size_t)18350080);       //  8,388,608  (end 26,738,688)

  hipLaunchKernelGGL(cvt_w_kernel, dim3(768), dim3(256), 0, stream,
                     (const float4*)wq, (const float4*)wk, (const float4*)wv, (u16x4*)Wb);
  hipLaunchKernelGGL(qkv_gemm_kernel, dim3(256), dim3(512), 0, stream, x, Wb, Qb, Kb, Vt);
  hipLaunchKernelGGL(attn_kernel, dim3(512), dim3(256), 0, stream, Qb, Kb, Vt, out);
}